// Round 6
// baseline (37.337 us; speedup 1.0000x reference)
//
#include <hip/hip_runtime.h>
#include <hip/hip_bf16.h>

#define BATCH 256
#define UNITS 64
#define IFEAT 256
#define OFEAT 256

typedef __attribute__((ext_vector_type(8))) short v8s;   // 8 bf16 (4 VGPRs)
typedef __attribute__((ext_vector_type(4))) float v4f;   // MFMA acc / global f32x4

// pack 2 floats -> u32 of 2 bf16 (RNE) — compiler emits v_cvt_pk_bf16_f32
static __device__ __forceinline__ unsigned int pk2(float a, float b) {
    union { __hip_bfloat162 h; unsigned int u; } c;
    c.h = __float22bfloat162_rn(float2{a, b});
    return c.u;
}

static __device__ __forceinline__ float sigmoid_f(float x) {
    return 1.0f / (1.0f + __expf(-x));
}
static __device__ __forceinline__ float tanh_f(float x) {
    float ax = fabsf(x);
    float e = __expf(-2.0f * ax);
    float t = (1.0f - e) / (1.0f + e);
    return copysignf(t, x);
}

// ---------------------------------------------------------------------------
// Kernel H: hvec[w][u][o] = sum_i hinit[u][i] * w_h{r,z,n}[u][i][o]
// 384 blocks x 512 threads streaming 50.3 MB coalesced (~8.5us, HBM-bound).
// ---------------------------------------------------------------------------
__global__ __launch_bounds__(512, 8) void gru_hvec(
        const float* __restrict__ whr,
        const float* __restrict__ whz,
        const float* __restrict__ whn,
        const float* __restrict__ hinit,
        float* __restrict__ hv) {
    __shared__ float red[512];
    const int bid  = blockIdx.x;
    const int half = bid & 1;
    const int u    = (bid >> 1) & 63;
    const int w    = bid >> 7;                     // 0..2
    const float* wh = (w == 0) ? whr : (w == 1) ? whz : whn;

    const int t = threadIdx.x;
    const int o = half * 128 + (t & 127);
    const int c = t >> 7;                          // i-quarter 0..3
    const float* hp = hinit + u * IFEAT;
    const float* wp = wh + (size_t)u * IFEAT * OFEAT + o;

    float acc = 0.0f;
    const int i0 = c * 64;
#pragma unroll 8
    for (int i = 0; i < 64; ++i) {
        acc += hp[i0 + i] * wp[(size_t)(i0 + i) * OFEAT];
    }
    red[t] = acc;
    __syncthreads();
    if (c == 0)
        hv[((size_t)w * UNITS + u) * OFEAT + o] =
            red[t] + red[t + 128] + red[t + 256] + red[t + 384];
}

// ---------------------------------------------------------------------------
// Kernel G: fused 3-way MFMA GEMM + GRU epilogue — zero-barrier main loop.
// BM=64, BN=32, full K=256 staged once. 512 threads = 8 waves (4m x 2n),
// wave tile 16x16. A staged row-per-instr (1KB coalesced dwordx4), B via
// pipelined register-transpose (2 chunks in flight). cvt_pk conversions.
// 80KB LDS -> 2 blocks/CU (16 waves). One __syncthreads total.
// grid = 2048 (64u x 4mb x 8nb), unit-major per XCD for L2 sharing.
// ---------------------------------------------------------------------------
__global__ __launch_bounds__(512, 4) void gru_gemm(
    const float* __restrict__ x,
    const float* __restrict__ wir,
    const float* __restrict__ wiz,
    const float* __restrict__ win,
    const float* __restrict__ hinit,
    const float* __restrict__ hv,
    float* __restrict__ out) {
    __shared__ unsigned short As[32][64][8];       // [kq][row'][j]   32 KB
    __shared__ unsigned short Bs[3][32][32][8];    // [g][kq][col][j] 48 KB

    const int bid = blockIdx.x;
    // XCD swizzle: xcd = bid&7 owns units [xcd*8, xcd*8+8).
    const int idx = bid >> 3;                  // 0..255 within XCD
    const int u   = (bid & 7) * 8 + (idx >> 5);
    const int rem = idx & 31;
    const int b0  = (rem >> 3) * 64;           // batch tile 0..3
    const int o0  = (rem & 7) * 32;            // out-feature tile 0..7

    const int t    = threadIdx.x;
    const int lane = t & 63;
    const int wv   = t >> 6;                   // 8 waves: 4m x 2n
    const int wm   = wv >> 1;                  // 0..3
    const int wn   = wv & 1;                   // 0/1
    const int lg   = lane >> 4;                // k-quad within step
    const int lr   = lane & 15;

    // ---- A loads: one row per instruction, 64 lanes x 16B = full 1KB row ----
    v4f areg[8];
#pragma unroll
    for (int i = 0; i < 8; ++i) {
        const int row = wv * 8 + i;
        areg[i] = *(const v4f*)(x + (size_t)(b0 + row) * (UNITS * IFEAT)
                                  + u * IFEAT + lane * 4);
    }

    // ---- B staging: pipelined register-transpose, 6 chunks of (8k x 1col) ----
    // chunk c: g = c>>1, kq = (c&1)*16 + (t>>5), col = t&31  (coalesced loads)
    const int bcol = t & 31;
    const int bkqh = t >> 5;                   // 0..15
    float rbA[8], rbB[8];

    auto bload = [&](int c, float* rb) {
        const int g  = c >> 1;
        const int kq = (c & 1) * 16 + bkqh;
        const float* wp = (g == 0) ? wir : (g == 1) ? wiz : win;
        const float* p = wp + (size_t)u * (IFEAT * OFEAT) + (kq * 8) * OFEAT + o0 + bcol;
#pragma unroll
        for (int j = 0; j < 8; ++j) rb[j] = p[j * OFEAT];
    };
    auto bstore = [&](int c, const float* rb) {
        const int g  = c >> 1;
        const int kq = (c & 1) * 16 + bkqh;
        uint4 v;
        v.x = pk2(rb[0], rb[1]);
        v.y = pk2(rb[2], rb[3]);
        v.z = pk2(rb[4], rb[5]);
        v.w = pk2(rb[6], rb[7]);
        *(uint4*)&Bs[g][kq][bcol][0] = v;
    };

    bload(0, rbA);
    bload(1, rbB);
    bstore(0, rbA);
    bload(2, rbA);
    bstore(1, rbB);
    bload(3, rbB);
    bstore(2, rbA);
    bload(4, rbA);
    bstore(3, rbB);
    bload(5, rbB);
    bstore(4, rbA);
    bstore(5, rbB);

    // ---- A stores: lane owns k = lane*4..+3 -> kq = lane>>1, j0 = (lane&1)*4
    {
        const int kqA = lane >> 1;
        const int j0  = (lane & 1) * 4;
#pragma unroll
        for (int i = 0; i < 8; ++i) {
            const int row = wv * 8 + i;
            const int rot = (row + kqA) & 63;
            uint2 v;
            v.x = pk2(areg[i][0], areg[i][1]);
            v.y = pk2(areg[i][2], areg[i][3]);
            *(uint2*)&As[kqA][rot][j0] = v;
        }
    }

    __syncthreads();   // the ONLY barrier

    // ---- barrier-free MFMA phase: 8 K-steps fully unrolled ----
    v4f acc[3];
#pragma unroll
    for (int g = 0; g < 3; ++g) acc[g] = (v4f){0.f, 0.f, 0.f, 0.f};

#pragma unroll
    for (int kk = 0; kk < 8; ++kk) {
        const int kq0 = kk * 4 + lg;
        v8s a0 = *(const v8s*)&As[kq0][((wm * 16 + lr) + kq0) & 63][0];
#pragma unroll
        for (int g = 0; g < 3; ++g) {
            v8s b = *(const v8s*)&Bs[g][kq0][wn * 16 + lr][0];
            acc[g] = __builtin_amdgcn_mfma_f32_16x16x32_bf16(a0, b, acc[g], 0, 0, 0);
        }
    }

    // ---- epilogue: GRU combine ----
    // C layout: col = lane&15, row = (lane>>4)*4 + reg
    const int o = o0 + wn * 16 + lr;
    const float hrv = hv[(0 * UNITS + u) * OFEAT + o];
    const float hzv = hv[(1 * UNITS + u) * OFEAT + o];
    const float hnv = hv[(2 * UNITS + u) * OFEAT + o];
    const float h0v = hinit[u * OFEAT + o];
    const int rbase = b0 + wm * 16 + lg * 4;
#pragma unroll
    for (int jj = 0; jj < 4; ++jj) {
        const int row = rbase + jj;
        const float r = sigmoid_f(acc[0][jj] + hrv);
        const float z = sigmoid_f(acc[1][jj] + hzv);
        const float n = tanh_f(acc[2][jj] + r * hnv);
        out[(row * UNITS + u) * OFEAT + o] = (1.0f - z) * n + z * h0v;
    }
}

extern "C" void kernel_launch(void* const* d_in, const int* in_sizes, int n_in,
                              void* d_out, int out_size, void* d_ws, size_t ws_size,
                              hipStream_t stream) {
    const float* x     = (const float*)d_in[0];
    const float* w_ir  = (const float*)d_in[1];
    const float* w_iz  = (const float*)d_in[2];
    const float* w_in  = (const float*)d_in[3];
    const float* w_hr  = (const float*)d_in[4];
    const float* w_hz  = (const float*)d_in[5];
    const float* w_hn  = (const float*)d_in[6];
    const float* hinit = (const float*)d_in[7];
    float* out = (float*)d_out;
    float* hv  = (float*)d_ws;   // 3*64*256 floats

    gru_hvec<<<dim3(384), dim3(512), 0, stream>>>(w_hr, w_hz, w_hn, hinit, hv);
    gru_gemm<<<dim3(2048), dim3(512), 0, stream>>>(x, w_ir, w_iz, w_in, hinit, hv, out);
}

// Round 7
// 34.673 us; speedup vs baseline: 1.0768x; 1.0768x over previous
//
#include <hip/hip_runtime.h>
#include <hip/hip_bf16.h>

#define UNITS 64
#define IFEAT 256
#define OFEAT 256

typedef __attribute__((ext_vector_type(8))) short v8s;   // 8 bf16 (4 VGPRs)
typedef __attribute__((ext_vector_type(4))) float v4f;   // MFMA acc / global f32x4

// pack 2 floats -> u32 of 2 bf16 (RNE) — compiler emits v_cvt_pk_bf16_f32
static __device__ __forceinline__ unsigned int pk2(float a, float b) {
    union { __hip_bfloat162 h; unsigned int u; } c;
    c.h = __float22bfloat162_rn(float2{a, b});
    return c.u;
}

static __device__ __forceinline__ float sigmoid_f(float x) {
    return 1.0f / (1.0f + __expf(-x));
}
static __device__ __forceinline__ float tanh_f(float x) {
    float ax = fabsf(x);
    float e = __expf(-2.0f * ax);
    float t = (1.0f - e) / (1.0f + e);
    return copysignf(t, x);
}

// ---------------------------------------------------------------------------
// Kernel H: hvec[w][u][o] = sum_i hinit[u][i] * w_h{r,z,n}[u][i][o]
// 384 blocks x 512 threads streaming 50.3 MB coalesced (~8.5us, HBM-bound).
// ---------------------------------------------------------------------------
__global__ __launch_bounds__(512, 8) void gru_hvec(
        const float* __restrict__ whr,
        const float* __restrict__ whz,
        const float* __restrict__ whn,
        const float* __restrict__ hinit,
        float* __restrict__ hv) {
    __shared__ float red[512];
    const int bid  = blockIdx.x;
    const int half = bid & 1;
    const int u    = (bid >> 1) & 63;
    const int w    = bid >> 7;                     // 0..2
    const float* wh = (w == 0) ? whr : (w == 1) ? whz : whn;

    const int t = threadIdx.x;
    const int o = half * 128 + (t & 127);
    const int c = t >> 7;                          // i-quarter 0..3
    const float* hp = hinit + u * IFEAT;
    const float* wp = wh + (size_t)u * IFEAT * OFEAT + o;

    float acc = 0.0f;
    const int i0 = c * 64;
#pragma unroll 8
    for (int i = 0; i < 64; ++i) {
        acc += hp[i0 + i] * wp[(size_t)(i0 + i) * OFEAT];
    }
    red[t] = acc;
    __syncthreads();
    if (c == 0)
        hv[((size_t)w * UNITS + u) * OFEAT + o] =
            red[t] + red[t + 128] + red[t + 256] + red[t + 384];
}

// ---------------------------------------------------------------------------
// Kernel G: fused 3-way MFMA GEMM + GRU epilogue.
// BM=128, BN=128, BK=32. 1024 threads = 16 waves (4m x 4n), wave tile 32x32.
// A (x tile) full-K resident in LDS: 64KB, rotated conflict-free layout.
// B (W) double-buffered per K-step: register-transpose, conflict-free b128.
// LDS 112KB -> exactly 1 block/CU; grid 256 = 64u x 2mb x 2nb = 1/CU.
// L2 traffic: W x2, x x2 = 131MB total (vs 327MB in R6).
// XCD swizzle: all 4 blocks of a unit on one XCD.
// ---------------------------------------------------------------------------
__global__ __launch_bounds__(1024, 4) void gru_gemm(
    const float* __restrict__ x,
    const float* __restrict__ wir,
    const float* __restrict__ wiz,
    const float* __restrict__ win,
    const float* __restrict__ hinit,
    const float* __restrict__ hv,
    float* __restrict__ out) {
    __shared__ unsigned short As[32][128][8];        // [kq][row'][j]       64 KB
    __shared__ unsigned short Bs[2][3][4][128][8];   // [buf][g][kq][col][j] 48 KB

    const int bid = blockIdx.x;
    // XCD swizzle: xcd = bid&7 owns units [xcd*8, xcd*8+8); 4 blocks/unit.
    const int idx = bid >> 3;                  // 0..31 within XCD
    const int u   = (bid & 7) * 8 + (idx >> 2);
    const int rem = idx & 3;
    const int b0  = (rem >> 1) * 128;          // batch tile 0..1
    const int o0  = (rem & 1) * 128;           // out-feature tile 0..1

    const int t    = threadIdx.x;
    const int lane = t & 63;
    const int wv   = t >> 6;                   // 16 waves: 4m x 4n
    const int wm   = wv >> 2;                  // 0..3
    const int wn   = wv & 3;                   // 0..3
    const int lg   = lane >> 4;                // k-quad within step
    const int lr   = lane & 15;

    // ---- B staging: 1536 col-vectors/step over 1024 threads ----
    // primary: col=t&127, kq=(t>>7)&3, g=t>>9 (0 or 1); secondary (t<512): g=2.
    const int bcol = t & 127;
    const int bkq  = (t >> 7) & 3;
    const int gA   = t >> 9;                   // wave-uniform
    const bool hasB = (wv < 8);                // wave-uniform
    const float* wpA = (gA == 0) ? wir : wiz;
    const size_t bgbase = (size_t)u * (IFEAT * OFEAT) + (bkq * 8) * OFEAT + o0 + bcol;

    float rbA[8], rbB[8];

    auto bload = [&](int kk) {
        const size_t off = bgbase + (size_t)kk * 32 * OFEAT;
#pragma unroll
        for (int j = 0; j < 8; ++j) rbA[j] = wpA[off + j * OFEAT];
        if (hasB) {
#pragma unroll
            for (int j = 0; j < 8; ++j) rbB[j] = win[off + j * OFEAT];
        }
    };
    auto bwrite = [&](int bb) {
        uint4 v;
        v.x = pk2(rbA[0], rbA[1]);
        v.y = pk2(rbA[2], rbA[3]);
        v.z = pk2(rbA[4], rbA[5]);
        v.w = pk2(rbA[6], rbA[7]);
        *(uint4*)&Bs[bb][gA][bkq][bcol][0] = v;
        if (hasB) {
            uint4 w;
            w.x = pk2(rbB[0], rbB[1]);
            w.y = pk2(rbB[2], rbB[3]);
            w.z = pk2(rbB[4], rbB[5]);
            w.w = pk2(rbB[6], rbB[7]);
            *(uint4*)&Bs[bb][2][bkq][bcol][0] = w;
        }
    };

    v4f acc[3][2][2];
#pragma unroll
    for (int g = 0; g < 3; ++g)
#pragma unroll
        for (int mi = 0; mi < 2; ++mi)
#pragma unroll
            for (int ni = 0; ni < 2; ++ni)
                acc[g][mi][ni] = (v4f){0.f, 0.f, 0.f, 0.f};

    // ---- prologue: B(0) in flight while A-tile staged (rows coalesced) ----
    bload(0);
    {
        const int kqA = lane >> 1;             // lane owns k = lane*4..+3
        const int j0  = (lane & 1) * 4;
#pragma unroll
        for (int i = 0; i < 8; ++i) {
            const int row = wv * 8 + i;
            v4f q = *(const v4f*)(x + (size_t)(b0 + row) * (UNITS * IFEAT)
                                    + u * IFEAT + lane * 4);
            uint2 w;
            w.x = pk2(q[0], q[1]);
            w.y = pk2(q[2], q[3]);
            *(uint2*)&As[kqA][(row + kqA) & 127][j0] = w;
        }
    }
    bwrite(0);
    bload(1);
    __syncthreads();

#pragma unroll
    for (int kk = 0; kk < 8; ++kk) {
        const int bb = kk & 1;
        if (kk < 7) bwrite(bb ^ 1);        // data for kk+1 into other buffer
        if (kk < 6) bload(kk + 2);         // refill regs; lands under MFMAs

        const int kq0 = kk * 4 + lg;
        v8s a0 = *(const v8s*)&As[kq0][((wm * 32 + lr) + kq0) & 127][0];
        v8s a1 = *(const v8s*)&As[kq0][((wm * 32 + 16 + lr) + kq0) & 127][0];
#pragma unroll
        for (int g = 0; g < 3; ++g) {
#pragma unroll
            for (int ni = 0; ni < 2; ++ni) {
                v8s b = *(const v8s*)&Bs[bb][g][lg][wn * 32 + ni * 16 + lr][0];
                acc[g][0][ni] = __builtin_amdgcn_mfma_f32_16x16x32_bf16(a0, b, acc[g][0][ni], 0, 0, 0);
                acc[g][1][ni] = __builtin_amdgcn_mfma_f32_16x16x32_bf16(a1, b, acc[g][1][ni], 0, 0, 0);
            }
        }
        if (kk < 7) __syncthreads();       // writes(bb^1) visible, reads(bb) done
    }

    // ---- epilogue: GRU combine ----
    // C layout: col = lane&15, row = (lane>>4)*4 + reg
    const int obase = o0 + wn * 32 + lr;
    float hrv[2], hzv[2], hnv[2], h0v[2];
#pragma unroll
    for (int ni = 0; ni < 2; ++ni) {
        const int o = obase + ni * 16;
        hrv[ni] = hv[(0 * UNITS + u) * OFEAT + o];
        hzv[ni] = hv[(1 * UNITS + u) * OFEAT + o];
        hnv[ni] = hv[(2 * UNITS + u) * OFEAT + o];
        h0v[ni] = hinit[u * OFEAT + o];
    }
    const int rbase = b0 + wm * 32 + lg * 4;
#pragma unroll
    for (int mi = 0; mi < 2; ++mi) {
#pragma unroll
        for (int ni = 0; ni < 2; ++ni) {
            const int o = obase + ni * 16;
#pragma unroll
            for (int jj = 0; jj < 4; ++jj) {
                const int row = rbase + mi * 16 + jj;
                const float r = sigmoid_f(acc[0][mi][ni][jj] + hrv[ni]);
                const float z = sigmoid_f(acc[1][mi][ni][jj] + hzv[ni]);
                const float n = tanh_f(acc[2][mi][ni][jj] + r * hnv[ni]);
                out[((size_t)row * UNITS + u) * OFEAT + o] = (1.0f - z) * n + z * h0v[ni];
            }
        }
    }
}

extern "C" void kernel_launch(void* const* d_in, const int* in_sizes, int n_in,
                              void* d_out, int out_size, void* d_ws, size_t ws_size,
                              hipStream_t stream) {
    const float* x     = (const float*)d_in[0];
    const float* w_ir  = (const float*)d_in[1];
    const float* w_iz  = (const float*)d_in[2];
    const float* w_in  = (const float*)d_in[3];
    const float* w_hr  = (const float*)d_in[4];
    const float* w_hz  = (const float*)d_in[5];
    const float* w_hn  = (const float*)d_in[6];
    const float* hinit = (const float*)d_in[7];
    float* out = (float*)d_out;
    float* hv  = (float*)d_ws;   // 3*64*256 floats

    gru_hvec<<<dim3(384), dim3(512), 0, stream>>>(w_hr, w_hz, w_hn, hinit, hv);
    gru_gemm<<<dim3(256), dim3(1024), 0, stream>>>(x, w_ir, w_iz, w_in, hinit, hv, out);
}